// Round 8
// baseline (231.724 us; speedup 1.0000x reference)
//
#include <hip/hip_runtime.h>
#include <cstdint>
#include <cstddef>

// SSMLayer, round 13:
//   prep_all -> prep2_fused (weight GEMMs || LN) -> gemm_proj (BM=128:
//   Bx fusion + chunk carries) -> scan_prefix (tiny: carry->prefix scan)
//   -> gemm_out (fused scan replay prologue + round-10 K-loop + nt epilogue).
// Round-13 vs round-12 (post-mortem: fusion was a wash -- gemm_out 46->70us
// ate the ~24us saved; cost = serial carry-prefix recombine (up to 255
// strided L2 reads, x4 redundant) on the critical path + regular resid loads
// re-adding 28MB write-allocate FETCH):
//   * scan_prefix kernel (8 blocks x 64 thr, ~2-3us): scans the 256 chunk
//     carries per chain into prefixT = carry-in per chunk (16-wide batched
//     loads). gemm_out prologue reads ONE float instead of the O(c) loop.
//   * gemm_out: B(kt=0) staging issued BEFORE the scan replay (prologue's
//     projP reads hide under B HBM latency); nontemporal resid/out restored.
//   * Everything else verbatim from passing round-12.

typedef unsigned short bf16_t;
typedef __attribute__((ext_vector_type(8))) short bh8;
typedef __attribute__((ext_vector_type(4))) float f4;

#define M_ROWS 32768
#define SCAN_L 16
#define SCAN_C 256   // 4096 / SCAN_L

__device__ __forceinline__ unsigned short f2bf(float f) {
  union { float f; unsigned int u; } c; c.f = f;
  unsigned int u = c.u;
  return (unsigned short)((u + 0x7FFFu + ((u >> 16) & 1u)) >> 16);
}

__device__ __forceinline__ uint2 pack4bf(f4 a) {
  uint2 r;
  r.x = (unsigned)f2bf(a[0]) | ((unsigned)f2bf(a[1]) << 16);
  r.y = (unsigned)f2bf(a[2]) | ((unsigned)f2bf(a[3]) << 16);
  return r;
}

__device__ __forceinline__ void async_cp16(void* lds, const void* g) {
  __builtin_amdgcn_global_load_lds((const __attribute__((address_space(1))) void*)g,
                                   (__attribute__((address_space(3))) void*)lds, 16, 0, 0);
}

// ---------------- prep_all: loop-free casts/transposes/zeros ----------------
// s0 262144: Wout_t[n][k]  = bf16(W_out[k][n])
// s1 262144: Wdout_t[n][k] = bf16(D_skip[k]*W_out[k][n])
// s2 262144: Win_b[d][j]   = bf16(W_in[d][j])
// s3  65536: Win_b[512+r][j] = r==0 ? bf16(b_in[j]) : 0   (rows 512..639)
// s4  65536: Wso_b[k][j]   = k<64 ? bf16(W_so[k][j]) : 0  (rows 0..127)
// s5 131072: Wcat_t[n][k] PERMUTED: n<128: g=n>>5,w=n&31: w<16 -> xs[g*16+w],
//            else B[g*16+w-16]; n in [128,192): C[n-128]; n>=192: 0
// s6  32768: Wproj[192+r][d] = 0                          (pad rows 192..255)
// s7     64: Abar = exp(-exp(A_log)), Apow = Abar^SCAN_L
__global__ __launch_bounds__(256) void prep_all(
    const float* __restrict__ W_in, const float* __restrict__ W_out,
    const float* __restrict__ W_so, const float* __restrict__ W_xs,
    const float* __restrict__ W_B,  const float* __restrict__ W_C,
    const float* __restrict__ b_in, const float* __restrict__ D_skip,
    const float* __restrict__ A_log,
    bf16_t* __restrict__ Wout_t, bf16_t* __restrict__ Wdout_t,
    bf16_t* __restrict__ Win_b, bf16_t* __restrict__ Wso_b,
    bf16_t* __restrict__ Wcat_t, bf16_t* __restrict__ Wproj,
    float* __restrict__ Abar, float* __restrict__ Apow) {
  int i = blockIdx.x * 256 + threadIdx.x;
  if (i < 262144) { int k = i >> 9, n = i & 511;
    Wout_t[(size_t)n * 512 + k] = f2bf(W_out[k * 512 + n]); return; }
  i -= 262144;
  if (i < 262144) { int k = i >> 9, n = i & 511;
    Wdout_t[(size_t)n * 512 + k] = f2bf(D_skip[k] * W_out[k * 512 + n]); return; }
  i -= 262144;
  if (i < 262144) { Win_b[i] = f2bf(W_in[i]); return; }
  i -= 262144;
  if (i < 65536) { int r = i >> 9, j = i & 511;
    Win_b[(size_t)(512 + r) * 512 + j] = (r == 0) ? f2bf(b_in[j]) : (bf16_t)0; return; }
  i -= 65536;
  if (i < 65536) { int k = i >> 9, j = i & 511;
    Wso_b[i] = (k < 64) ? f2bf(W_so[k * 512 + j]) : (bf16_t)0; return; }
  i -= 65536;
  if (i < 131072) { int k = i >> 8, n = i & 255;
    float v = 0.f;
    if (n < 128) { int g = n >> 5, w = n & 31;
      v = (w < 16) ? W_xs[k * 64 + g * 16 + w] : W_B[k * 64 + g * 16 + (w - 16)];
    } else if (n < 192) v = W_C[k * 64 + n - 128];
    Wcat_t[(size_t)n * 512 + k] = f2bf(v); return; }
  i -= 131072;
  if (i < 32768) { int r = i >> 9, d = i & 511;
    Wproj[(size_t)(192 + r) * 512 + d] = 0; return; }
  i -= 32768;
  if (i < 64) {
    float a = __expf(A_log[i]);
    Abar[i] = __expf(-a);
    Apow[i] = __expf(-a * (float)SCAN_L);
  }
}

// ---------------- prep2_fused: weight GEMMs (blocks 0..33) || LN (34..8225) ----
__global__ __launch_bounds__(256, 4) void prep2_fused(
    const bf16_t* __restrict__ Win_b, const bf16_t* __restrict__ Wcat_t,
    const bf16_t* __restrict__ Wso_b, const bf16_t* __restrict__ Wout_t,
    const bf16_t* __restrict__ Wdout_t,
    const float* __restrict__ b_B, const float* __restrict__ b_C,
    bf16_t* __restrict__ Wproj, bf16_t* __restrict__ Wcat2,
    float* __restrict__ biasp, float* __restrict__ biasW2,
    const float* __restrict__ x, const float* __restrict__ gamma,
    const float* __restrict__ beta, bf16_t* __restrict__ xn) {
  __shared__ __align__(16) bf16_t As[128 * 64];
  __shared__ __align__(16) bf16_t Bs[128 * 64];
  const int tid = threadIdx.x;

  if (blockIdx.x >= 34) {
    // -------- LayerNorm branch --------
    const int row = (int)(blockIdx.x - 34) * 4 + (tid >> 6);
    const int lane = tid & 63;
    const float* xr = x + (size_t)row * 512 + lane * 8;
    float4 v0 = *(const float4*)xr;
    float4 v1 = *(const float4*)(xr + 4);
    float s  = v0.x + v0.y + v0.z + v0.w + v1.x + v1.y + v1.z + v1.w;
    float sq = v0.x*v0.x + v0.y*v0.y + v0.z*v0.z + v0.w*v0.w
             + v1.x*v1.x + v1.y*v1.y + v1.z*v1.z + v1.w*v1.w;
    #pragma unroll
    for (int off = 32; off > 0; off >>= 1) {
      s  += __shfl_xor(s, off, 64);
      sq += __shfl_xor(sq, off, 64);
    }
    const float mu  = s * (1.0f / 512.0f);
    const float var = sq * (1.0f / 512.0f) - mu * mu;
    const float rs  = rsqrtf(var + 1e-3f);
    float4 g0 = *(const float4*)(gamma + lane * 8);
    float4 g1 = *(const float4*)(gamma + lane * 8 + 4);
    float4 b0 = *(const float4*)(beta + lane * 8);
    float4 b1 = *(const float4*)(beta + lane * 8 + 4);
    bh8 ov;
    ov[0] = (short)f2bf((v0.x - mu) * rs * g0.x + b0.x);
    ov[1] = (short)f2bf((v0.y - mu) * rs * g0.y + b0.y);
    ov[2] = (short)f2bf((v0.z - mu) * rs * g0.z + b0.z);
    ov[3] = (short)f2bf((v0.w - mu) * rs * g0.w + b0.w);
    ov[4] = (short)f2bf((v1.x - mu) * rs * g1.x + b1.x);
    ov[5] = (short)f2bf((v1.y - mu) * rs * g1.y + b1.y);
    ov[6] = (short)f2bf((v1.z - mu) * rs * g1.z + b1.z);
    ov[7] = (short)f2bf((v1.w - mu) * rs * g1.w + b1.w);
    *(bh8*)(xn + (size_t)row * 512 + lane * 8) = ov;
    return;
  }

  // -------- weight-GEMM branch --------
  const int bx = blockIdx.x;
  const int wave = tid >> 6, lane = tid & 63;
  const int quad = lane >> 4, l16 = lane & 15;
  const int wm = (wave >> 1) * 64, wn = (wave & 1) * 64;
  int role, mb, nb;
  if (bx < 10)      { role = 0; mb = bx >> 1; nb = bx & 1; }
  else if (bx < 14) { role = 1; mb = 0; nb = bx - 10; }
  else { role = 2; int t = bx - 14; mb = t >> 2; nb = t & 3; }
  const bf16_t* Ap = (role == 1) ? Wso_b : Win_b;
  const bf16_t* Bp = (role == 0) ? Wcat_t : (role == 1) ? Wout_t : Wdout_t;

  f4 acc[4][4];
  #pragma unroll
  for (int i = 0; i < 4; ++i)
    #pragma unroll
    for (int j = 0; j < 4; ++j) acc[i][j] = (f4){0.f, 0.f, 0.f, 0.f};

  for (int kt = 0; kt < 8; ++kt) {
    const int k0 = kt << 6;
    __syncthreads();
    #pragma unroll
    for (int i = 0; i < 4; ++i) {
      const int base = (wave * 4 + i) * 64;
      const int cid = base + lane;
      const int row = cid >> 3;
      const int g = (cid & 7) ^ (row & 7);
      async_cp16((char*)As + base * 16,
                 Ap + (size_t)(mb * 128 + row) * 512 + k0 + g * 8);
    }
    #pragma unroll
    for (int i = 0; i < 4; ++i) {
      const int base = (wave * 4 + i) * 64;
      const int cid = base + lane;
      const int row = cid >> 3;
      const int g = (cid & 7) ^ (row & 7);
      async_cp16((char*)Bs + base * 16,
                 Bp + (size_t)(nb * 128 + row) * 512 + k0 + g * 8);
    }
    __syncthreads();
    #pragma unroll
    for (int ks = 0; ks < 2; ++ks) {
      const int gb = ks * 4 + quad;
      bh8 af[4], bfv[4];
      #pragma unroll
      for (int im = 0; im < 4; ++im) {
        const int row = wm + im * 16 + l16;
        af[im] = *(const bh8*)((const char*)As + row * 128 + ((gb ^ (row & 7)) * 16));
      }
      #pragma unroll
      for (int in_ = 0; in_ < 4; ++in_) {
        const int row = wn + in_ * 16 + l16;
        bfv[in_] = *(const bh8*)((const char*)Bs + row * 128 + ((gb ^ (row & 7)) * 16));
      }
      #pragma unroll
      for (int im = 0; im < 4; ++im)
        #pragma unroll
        for (int in_ = 0; in_ < 4; ++in_)
          acc[im][in_] = __builtin_amdgcn_mfma_f32_16x16x32_bf16(af[im], bfv[in_],
                                                                 acc[im][in_], 0, 0, 0);
    }
  }

  #pragma unroll
  for (int im = 0; im < 4; ++im) {
    #pragma unroll
    for (int in_ = 0; in_ < 4; ++in_) {
      const int row0 = mb * 128 + wm + im * 16 + quad * 4;
      const int col = nb * 128 + wn + in_ * 16 + l16;
      if (role == 0) {
        if (col < 192) {
          if (row0 < 512) {
            *(uint2*)(Wproj + (size_t)col * 512 + row0) = pack4bf(acc[im][in_]);
          } else if (row0 == 512) {
            float v = acc[im][in_][0];
            if (col < 128) { int w = col & 31;
              if (w >= 16) v += b_B[(col >> 5) * 16 + (w - 16)];
            } else v += b_C[col - 128];
            biasp[col] = v;
          }
        }
      } else if (role == 1) {
        if (row0 < 64)
          *(uint2*)(Wcat2 + (size_t)col * 576 + row0) = pack4bf(acc[im][in_]);
      } else {
        if (row0 < 512) {
          *(uint2*)(Wcat2 + (size_t)col * 576 + 64 + row0) = pack4bf(acc[im][in_]);
        } else if (row0 == 512) {
          biasW2[col] = acc[im][in_][0];
        }
      }
    }
  }
}

// ---------------- gemm_proj: 128x128 tile, BK=64 ----------------------------
// projP = xn @ Wproj^T (+biasp). grid (256,2).
//   nb==0: interleaved xs/B cols -> Bx = xs*B, plane 0, + fused chunk carries.
//   nb==1: cols 128..191 (C) -> plane 1 (wn==0 waves only).
__global__ __launch_bounds__(256, 4) void gemm_proj(
    const bf16_t* __restrict__ A0, const bf16_t* __restrict__ Wt,
    float* __restrict__ outf, const float* __restrict__ bias1,
    const float* __restrict__ Abar, float* __restrict__ carryT) {
  __shared__ __align__(16) char smem[32768];
  bf16_t* As = (bf16_t*)smem;
  bf16_t* Bs = (bf16_t*)(smem + 16384);
  const int tid = threadIdx.x;
  const int wave = tid >> 6, lane = tid & 63;
  const int quad = lane >> 4, l16 = lane & 15;
  const int wm = (wave >> 1) * 64, wn = (wave & 1) * 64;
  const int mb = blockIdx.x, nb = blockIdx.y;
  const int K = 512;

  f4 acc[4][4];
  #pragma unroll
  for (int i = 0; i < 4; ++i)
    #pragma unroll
    for (int j = 0; j < 4; ++j) acc[i][j] = (f4){0.f, 0.f, 0.f, 0.f};

  for (int kt = 0; kt < 8; ++kt) {
    const int k0 = kt << 6;
    __syncthreads();
    #pragma unroll
    for (int i = 0; i < 4; ++i) {
      const int base = (wave * 4 + i) * 64;
      const int cid = base + lane;
      const int row = cid >> 3;
      const int g = (cid & 7) ^ (row & 7);
      async_cp16((char*)As + base * 16,
                 A0 + (size_t)(mb * 128 + row) * K + k0 + g * 8);
    }
    #pragma unroll
    for (int i = 0; i < 4; ++i) {
      const int base = (wave * 4 + i) * 64;
      const int cid = base + lane;
      const int row = cid >> 3;
      const int g = (cid & 7) ^ (row & 7);
      async_cp16((char*)Bs + base * 16,
                 Wt + (size_t)(nb * 128 + row) * K + k0 + g * 8);
    }
    __syncthreads();

    #pragma unroll
    for (int ks = 0; ks < 2; ++ks) {
      const int gb = ks * 4 + quad;
      bh8 af[4], bfv[4];
      #pragma unroll
      for (int im = 0; im < 4; ++im) {
        const int row = wm + im * 16 + l16;
        af[im] = *(const bh8*)((const char*)As + row * 128 + ((gb ^ (row & 7)) * 16));
      }
      #pragma unroll
      for (int in_ = 0; in_ < 4; ++in_) {
        const int row = wn + in_ * 16 + l16;
        bfv[in_] = *(const bh8*)((const char*)Bs + row * 128 + ((gb ^ (row & 7)) * 16));
      }
      #pragma unroll
      for (int im = 0; im < 4; ++im)
        #pragma unroll
        for (int in_ = 0; in_ < 4; ++in_)
          acc[im][in_] = __builtin_amdgcn_mfma_f32_16x16x32_bf16(af[im], bfv[in_],
                                                                 acc[im][in_], 0, 0, 0);
    }
  }

  __syncthreads();
  float* lt = (float*)smem;

  if (nb == 0) {
    // interleaved xs/B: fuse Bx = xs*B into wave-private LDS tile
    float* wb = lt + wave * 2048;            // 64 rows x 32 chains fp32 = 8KB
    #pragma unroll
    for (int im = 0; im < 4; ++im)
      #pragma unroll
      for (int pp = 0; pp < 2; ++pp)
        #pragma unroll
        for (int r = 0; r < 4; ++r) {
          const int c0 = wn + (2 * pp) * 16 + l16;
          const float vx = acc[im][2 * pp][r]     + bias1[c0];
          const float vb = acc[im][2 * pp + 1][r] + bias1[c0 + 16];
          wb[(im * 16 + quad * 4 + r) * 32 + pp * 16 + l16] = vx * vb;
        }
    const int rsub = lane >> 3, cg8 = lane & 7;
    #pragma unroll
    for (int rr = 0; rr < 8; ++rr) {
      const int rl = rr * 8 + rsub;
      f4 v = *(f4*)(wb + rl * 32 + cg8 * 4);
      const size_t row = (size_t)(mb * 128 + wm + rl);
      *(f4*)(outf + row * 64 + (wn >> 1) + cg8 * 4) = v;
    }
    // fused chunk-local scan carries (16-step chunks from the LDS Bx tile)
    {
      const int bb = mb >> 5;                       // batch (32 blocks/batch)
      const int cbase = (mb & 31) * 8 + (wm >> 4);  // first chunk of this wave
      const int ch = lane & 31;                     // chain_local
      const int n = (wn >> 1) + ch;                 // global chain 0..63
      const float A = Abar[n];
      #pragma unroll
      for (int t = 0; t < 2; ++t) {
        const int cl = (lane >> 5) + 2 * t;         // chunk_local 0..3
        float hv = 0.f;
        #pragma unroll
        for (int i = 0; i < SCAN_L; ++i)
          hv = fmaf(A, hv, wb[(cl * SCAN_L + i) * 32 + ch]);
        carryT[(size_t)(cbase + cl) * 512 + bb * 64 + n] = hv;
      }
    }
  } else if (wn == 0) {
    // C plane: global cols 128..191 -> chains 0..63 (waves 0 and 2 only)
    float* wb = lt + (wave >> 1) * 4096;     // 64 rows x 64 chains fp32 = 16KB
    #pragma unroll
    for (int im = 0; im < 4; ++im)
      #pragma unroll
      for (int in_ = 0; in_ < 4; ++in_)
        #pragma unroll
        for (int r = 0; r < 4; ++r) {
          const int c = in_ * 16 + l16;
          wb[(im * 16 + quad * 4 + r) * 64 + c] = acc[im][in_][r] + bias1[128 + c];
        }
    #pragma unroll
    for (int rr = 0; rr < 16; ++rr) {
      const int rl = rr * 4 + quad;
      f4 v = *(f4*)(wb + rl * 64 + l16 * 4);
      const size_t row = (size_t)(mb * 128 + wm + rl);
      *(f4*)(outf + ((size_t)M_ROWS + row) * 64 + l16 * 4) = v;
    }
  }
}

// ---------------- scan_prefix: carries -> per-chunk carry-in prefix ----------
// One block per batch bb; lane = chain n. Serial over SCAN_C chunks with
// 16-wide batched loads (loads are independent of the fma chain).
// prefixT[c*512 + bb*64 + n] = carry-in h for chunk c of (bb, n).
__global__ __launch_bounds__(64) void scan_prefix(
    const float* __restrict__ carryT, const float* __restrict__ Apow,
    float* __restrict__ prefixT) {
  const int bb = blockIdx.x, n = threadIdx.x;
  const float Ap = Apow[n];
  const float* cr = carryT + bb * 64 + n;
  float* pf = prefixT + bb * 64 + n;
  float h = 0.f;
  for (int c = 0; c < SCAN_C; c += 16) {
    float v[16];
    #pragma unroll
    for (int i = 0; i < 16; ++i) v[i] = cr[(size_t)(c + i) * 512];
    #pragma unroll
    for (int i = 0; i < 16; ++i) {
      pf[(size_t)(c + i) * 512] = h;
      h = fmaf(Ap, h, v[i]);
    }
  }
}

// ---------------- gemm_out: 64x128 tile, BK=64, FUSED scan replay ------------
// out = [CH|xn] @ Wcat2^T + b_out + biasW2 + x   (K=576), grid (512,4).
// Prologue: B(kt=0) staging issued first (prologue hides under its latency);
// each block replays its 64-row CH tile (carry-in from prefixT, 16-step
// replay from projP planes), writing bf16 XOR-swizzled into As via ds_write.
// K-loop = round-10 single-buffer 2-barrier; epilogue scalar + nontemporal.
__global__ __launch_bounds__(256, 4) void gemm_out(
    const float* __restrict__ projP, const float* __restrict__ Abar,
    const float* __restrict__ prefixT,
    const bf16_t* __restrict__ xn, const bf16_t* __restrict__ Wt,
    float* __restrict__ outf,
    const float* __restrict__ bias0, const float* __restrict__ bias1,
    const float* __restrict__ resid) {
  __shared__ __align__(16) bf16_t As[64 * 64];    // 8KB (CH tile / xn tiles)
  __shared__ __align__(16) bf16_t Bs[128 * 64];   // 16KB
  const int tid = threadIdx.x;
  const int wave = tid >> 6, lane = tid & 63;
  const int quad = lane >> 4, l16 = lane & 15;
  const int wm = (wave >> 1) * 32, wn = (wave & 1) * 64;
  const int mb = blockIdx.x, nb = blockIdx.y;
  const int K = 576;

  // ---- pre-issue B staging for kt=0 (prologue hides under its latency)
  #pragma unroll
  for (int i = 0; i < 4; ++i) {
    const int base = (wave * 4 + i) * 64;
    const int cid = base + lane;
    const int row = cid >> 3;
    const int g = (cid & 7) ^ (row & 7);
    async_cp16((char*)Bs + base * 16,
               Wt + (size_t)(nb * 128 + row) * K + g * 8);
  }

  // ---- scan replay prologue: CH[mb*64 + r][n], r=0..63, n=0..63.
  // Thread map: wave = chunk_local (4 chunks of 16 rows), lane = chain n.
  {
    const int n = lane;
    const int cl = wave;
    const int bb = mb >> 6;                       // batch (64 blocks/batch)
    const int c0 = (mb & 63) * 4 + cl;            // chunk index in batch
    const float A = Abar[n];
    float h = prefixT[(size_t)c0 * 512 + bb * 64 + n];
    const size_t row0 = (size_t)mb * 64 + cl * 16;      // global row of step 0
    const float* pBx = projP + row0 * 64;
    const float* pC  = projP + ((size_t)M_ROWS + row0) * 64;
    char* asb = (char*)As;
    const int g = n >> 3, boff = (n & 7) * 2;
    #pragma unroll
    for (int i = 0; i < SCAN_L; ++i) {
      h = fmaf(A, h, pBx[i * 64 + n]);
      const int row = cl * 16 + i;
      *(bf16_t*)(asb + row * 128 + ((g ^ (row & 7)) * 16) + boff) =
          f2bf(pC[i * 64 + n] * h);
    }
  }

  f4 acc[2][4];
  #pragma unroll
  for (int i = 0; i < 2; ++i)
    #pragma unroll
    for (int j = 0; j < 4; ++j) acc[i][j] = (f4){0.f, 0.f, 0.f, 0.f};

  for (int kt = 0; kt < 9; ++kt) {
    const int k0 = kt << 6;
    if (kt > 0) {
      __syncthreads();                          // guard LDS before overwrite
      #pragma unroll
      for (int i = 0; i < 2; ++i) {             // A: xn tile
        const int base = (wave * 2 + i) * 64;
        const int cid = base + lane;
        const int row = cid >> 3;
        const int g = (cid & 7) ^ (row & 7);
        async_cp16((char*)As + base * 16,
                   xn + (size_t)(mb * 64 + row) * 512 + (k0 - 64) + g * 8);
      }
      #pragma unroll
      for (int i = 0; i < 4; ++i) {             // B: 128 rows, 16KB
        const int base = (wave * 4 + i) * 64;
        const int cid = base + lane;
        const int row = cid >> 3;
        const int g = (cid & 7) ^ (row & 7);
        async_cp16((char*)Bs + base * 16,
                   Wt + (size_t)(nb * 128 + row) * K + k0 + g * 8);
      }
    }
    __syncthreads();                            // publish stage (and prologue)

    #pragma unroll
    for (int ks = 0; ks < 2; ++ks) {
      const int gb = ks * 4 + quad;
      bh8 af[2], bfv[4];
      #pragma unroll
      for (int im = 0; im < 2; ++im) {
        const int row = wm + im * 16 + l16;
        af[im] = *(const bh8*)((const char*)As + row * 128 + ((gb ^ (row & 7)) * 16));
      }
      #pragma unroll
      for (int in_ = 0; in_ < 4; ++in_) {
        const int row = wn + in_ * 16 + l16;
        bfv[in_] = *(const bh8*)((const char*)Bs + row * 128 + ((gb ^ (row & 7)) * 16));
      }
      #pragma unroll
      for (int im = 0; im < 2; ++im)
        #pragma unroll
        for (int in_ = 0; in_ < 4; ++in_)
          acc[im][in_] = __builtin_amdgcn_mfma_f32_16x16x32_bf16(af[im], bfv[in_],
                                                                 acc[im][in_], 0, 0, 0);
    }
  }

  // ---- direct epilogue: acc layout col=l16, row=quad*4+reg. Scalar I/O,
  // nontemporal (out/resid never re-read; avoids L2 write-allocate pollution).
  #pragma unroll
  for (int im = 0; im < 2; ++im) {
    #pragma unroll
    for (int in_ = 0; in_ < 4; ++in_) {
      const int col = nb * 128 + wn + in_ * 16 + l16;
      const float bsum = bias0[col] + bias1[col];
      #pragma unroll
      for (int r = 0; r < 4; ++r) {
        const int row = mb * 64 + wm + im * 16 + quad * 4 + r;
        const size_t idx = (size_t)row * 512 + col;
        const float rv = __builtin_nontemporal_load(resid + idx);
        __builtin_nontemporal_store(acc[im][in_][r] + bsum + rv, outf + idx);
      }
    }
  }
}

// ---------------- launch ----------------
extern "C" void kernel_launch(void* const* d_in, const int* in_sizes, int n_in,
                              void* d_out, int out_size, void* d_ws, size_t ws_size,
                              hipStream_t stream) {
  const float* x      = (const float*)d_in[0];
  const float* ln_g   = (const float*)d_in[1];
  const float* ln_b   = (const float*)d_in[2];
  const float* W_in   = (const float*)d_in[3];
  const float* b_in   = (const float*)d_in[4];
  const float* W_xs   = (const float*)d_in[5];
  const float* W_B    = (const float*)d_in[6];
  const float* b_B    = (const float*)d_in[7];
  const float* W_C    = (const float*)d_in[8];
  const float* b_C    = (const float*)d_in[9];
  const float* A_log  = (const float*)d_in[10];
  const float* D_skip = (const float*)d_in[11];
  const float* W_so   = (const float*)d_in[12];
  const float* W_out  = (const float*)d_in[13];
  const float* b_out  = (const float*)d_in[14];
  float* out = (float*)d_out;

  char* w = (char*)d_ws;
  auto carve = [&](size_t bytes) {
    char* p = w; w += (bytes + 255) & ~(size_t)255; return p;
  };
  bf16_t* xn     = (bf16_t*)carve((size_t)M_ROWS * 512 * 2);
  float*  projP  = (float*)carve((size_t)2 * M_ROWS * 64 * 4);
  float*  carryT = (float*)carve((size_t)SCAN_C * 512 * 4);
  float*  prefixT= (float*)carve((size_t)SCAN_C * 512 * 4);
  bf16_t* Wproj  = (bf16_t*)carve((size_t)256 * 512 * 2);
  bf16_t* Wcat2  = (bf16_t*)carve((size_t)512 * 576 * 2);
  bf16_t* Win_b  = (bf16_t*)carve((size_t)640 * 512 * 2);
  bf16_t* Wso_b  = (bf16_t*)carve((size_t)128 * 512 * 2);
  bf16_t* Wout_t = (bf16_t*)carve((size_t)512 * 512 * 2);
  bf16_t* Wdout_t= (bf16_t*)carve((size_t)512 * 512 * 2);
  bf16_t* Wcat_t = (bf16_t*)carve((size_t)256 * 512 * 2);
  float*  biasp  = (float*)carve(192 * 4);
  float*  biasW2 = (float*)carve(512 * 4);
  float*  Abar   = (float*)carve(256);
  float*  Apow   = (float*)carve(256);

  prep_all<<<4227, 256, 0, stream>>>(W_in, W_out, W_so, W_xs, W_B, W_C, b_in,
                                     D_skip, A_log, Wout_t, Wdout_t, Win_b,
                                     Wso_b, Wcat_t, Wproj, Abar, Apow);
  prep2_fused<<<34 + 8192, 256, 0, stream>>>(Win_b, Wcat_t, Wso_b, Wout_t,
                                             Wdout_t, b_B, b_C, Wproj, Wcat2,
                                             biasp, biasW2, x, ln_g, ln_b, xn);
  gemm_proj<<<dim3(256, 2), 256, 0, stream>>>(xn, Wproj, projP, biasp,
                                              Abar, carryT);
  scan_prefix<<<8, 64, 0, stream>>>(carryT, Apow, prefixT);
  gemm_out<<<dim3(512, 4), 256, 0, stream>>>(projP, Abar, prefixT,
                                             xn, Wcat2, out,
                                             b_out, biasW2, x);
}

// Round 9
// 215.445 us; speedup vs baseline: 1.0756x; 1.0756x over previous
//
#include <hip/hip_runtime.h>
#include <cstdint>
#include <cstddef>

// SSMLayer, round 14:
//   prep_all -> prep2_fused (weight GEMMs || LN) -> gemm_proj (BM=128,
//   Bx fusion + chunk carries, XCD-grouped decode) -> scan_apply ->
//   gemm_out (BM=64, round-10 K-loop, XCD-grouped decode, nt-load epilogue).
// Round-14 vs round-13 (post-mortem: fused replay's x4 projP re-read on
// different XCDs + extra launch made it worse; nt STORES inflate WRITE by
// 15-20MB (R8/R13 vs R10/R12); base reverts to round-10 = 219.5us):
//   * gemm_out + gemm_proj: XCD-grouped 1D decode (nb innermost per XCD) --
//     nb-siblings sharing an A-tile run adjacently on one XCD's L2
//     (T1/catalog; round-7 showed FETCH 69->55 but was confounded; this is
//     the isolated test).
//   * gemm_out epilogue: nontemporal resid LOAD, REGULAR out store.
//   * Everything else verbatim round-10 (banked 219.5, all-passing).

typedef unsigned short bf16_t;
typedef __attribute__((ext_vector_type(8))) short bh8;
typedef __attribute__((ext_vector_type(4))) float f4;

#define M_ROWS 32768
#define SCAN_L 16
#define SCAN_C 256   // 4096 / SCAN_L

__device__ __forceinline__ unsigned short f2bf(float f) {
  union { float f; unsigned int u; } c; c.f = f;
  unsigned int u = c.u;
  return (unsigned short)((u + 0x7FFFu + ((u >> 16) & 1u)) >> 16);
}

__device__ __forceinline__ uint2 pack4bf(f4 a) {
  uint2 r;
  r.x = (unsigned)f2bf(a[0]) | ((unsigned)f2bf(a[1]) << 16);
  r.y = (unsigned)f2bf(a[2]) | ((unsigned)f2bf(a[3]) << 16);
  return r;
}

__device__ __forceinline__ void async_cp16(void* lds, const void* g) {
  __builtin_amdgcn_global_load_lds((const __attribute__((address_space(1))) void*)g,
                                   (__attribute__((address_space(3))) void*)lds, 16, 0, 0);
}

// ---------------- prep_all: loop-free casts/transposes/zeros ----------------
// s0 262144: Wout_t[n][k]  = bf16(W_out[k][n])
// s1 262144: Wdout_t[n][k] = bf16(D_skip[k]*W_out[k][n])
// s2 262144: Win_b[d][j]   = bf16(W_in[d][j])
// s3  65536: Win_b[512+r][j] = r==0 ? bf16(b_in[j]) : 0   (rows 512..639)
// s4  65536: Wso_b[k][j]   = k<64 ? bf16(W_so[k][j]) : 0  (rows 0..127)
// s5 131072: Wcat_t[n][k] PERMUTED: n<128: g=n>>5,w=n&31: w<16 -> xs[g*16+w],
//            else B[g*16+w-16]; n in [128,192): C[n-128]; n>=192: 0
// s6  32768: Wproj[192+r][d] = 0                          (pad rows 192..255)
// s7     64: Abar = exp(-exp(A_log)), Apow = Abar^SCAN_L
__global__ __launch_bounds__(256) void prep_all(
    const float* __restrict__ W_in, const float* __restrict__ W_out,
    const float* __restrict__ W_so, const float* __restrict__ W_xs,
    const float* __restrict__ W_B,  const float* __restrict__ W_C,
    const float* __restrict__ b_in, const float* __restrict__ D_skip,
    const float* __restrict__ A_log,
    bf16_t* __restrict__ Wout_t, bf16_t* __restrict__ Wdout_t,
    bf16_t* __restrict__ Win_b, bf16_t* __restrict__ Wso_b,
    bf16_t* __restrict__ Wcat_t, bf16_t* __restrict__ Wproj,
    float* __restrict__ Abar, float* __restrict__ Apow) {
  int i = blockIdx.x * 256 + threadIdx.x;
  if (i < 262144) { int k = i >> 9, n = i & 511;
    Wout_t[(size_t)n * 512 + k] = f2bf(W_out[k * 512 + n]); return; }
  i -= 262144;
  if (i < 262144) { int k = i >> 9, n = i & 511;
    Wdout_t[(size_t)n * 512 + k] = f2bf(D_skip[k] * W_out[k * 512 + n]); return; }
  i -= 262144;
  if (i < 262144) { Win_b[i] = f2bf(W_in[i]); return; }
  i -= 262144;
  if (i < 65536) { int r = i >> 9, j = i & 511;
    Win_b[(size_t)(512 + r) * 512 + j] = (r == 0) ? f2bf(b_in[j]) : (bf16_t)0; return; }
  i -= 65536;
  if (i < 65536) { int k = i >> 9, j = i & 511;
    Wso_b[i] = (k < 64) ? f2bf(W_so[k * 512 + j]) : (bf16_t)0; return; }
  i -= 65536;
  if (i < 131072) { int k = i >> 8, n = i & 255;
    float v = 0.f;
    if (n < 128) { int g = n >> 5, w = n & 31;
      v = (w < 16) ? W_xs[k * 64 + g * 16 + w] : W_B[k * 64 + g * 16 + (w - 16)];
    } else if (n < 192) v = W_C[k * 64 + n - 128];
    Wcat_t[(size_t)n * 512 + k] = f2bf(v); return; }
  i -= 131072;
  if (i < 32768) { int r = i >> 9, d = i & 511;
    Wproj[(size_t)(192 + r) * 512 + d] = 0; return; }
  i -= 32768;
  if (i < 64) {
    float a = __expf(A_log[i]);
    Abar[i] = __expf(-a);
    Apow[i] = __expf(-a * (float)SCAN_L);
  }
}

// ---------------- prep2_fused: weight GEMMs (blocks 0..33) || LN (34..8225) ----
__global__ __launch_bounds__(256, 4) void prep2_fused(
    const bf16_t* __restrict__ Win_b, const bf16_t* __restrict__ Wcat_t,
    const bf16_t* __restrict__ Wso_b, const bf16_t* __restrict__ Wout_t,
    const bf16_t* __restrict__ Wdout_t,
    const float* __restrict__ b_B, const float* __restrict__ b_C,
    bf16_t* __restrict__ Wproj, bf16_t* __restrict__ Wcat2,
    float* __restrict__ biasp, float* __restrict__ biasW2,
    const float* __restrict__ x, const float* __restrict__ gamma,
    const float* __restrict__ beta, bf16_t* __restrict__ xn) {
  __shared__ __align__(16) bf16_t As[128 * 64];
  __shared__ __align__(16) bf16_t Bs[128 * 64];
  const int tid = threadIdx.x;

  if (blockIdx.x >= 34) {
    // -------- LayerNorm branch --------
    const int row = (int)(blockIdx.x - 34) * 4 + (tid >> 6);
    const int lane = tid & 63;
    const float* xr = x + (size_t)row * 512 + lane * 8;
    float4 v0 = *(const float4*)xr;
    float4 v1 = *(const float4*)(xr + 4);
    float s  = v0.x + v0.y + v0.z + v0.w + v1.x + v1.y + v1.z + v1.w;
    float sq = v0.x*v0.x + v0.y*v0.y + v0.z*v0.z + v0.w*v0.w
             + v1.x*v1.x + v1.y*v1.y + v1.z*v1.z + v1.w*v1.w;
    #pragma unroll
    for (int off = 32; off > 0; off >>= 1) {
      s  += __shfl_xor(s, off, 64);
      sq += __shfl_xor(sq, off, 64);
    }
    const float mu  = s * (1.0f / 512.0f);
    const float var = sq * (1.0f / 512.0f) - mu * mu;
    const float rs  = rsqrtf(var + 1e-3f);
    float4 g0 = *(const float4*)(gamma + lane * 8);
    float4 g1 = *(const float4*)(gamma + lane * 8 + 4);
    float4 b0 = *(const float4*)(beta + lane * 8);
    float4 b1 = *(const float4*)(beta + lane * 8 + 4);
    bh8 ov;
    ov[0] = (short)f2bf((v0.x - mu) * rs * g0.x + b0.x);
    ov[1] = (short)f2bf((v0.y - mu) * rs * g0.y + b0.y);
    ov[2] = (short)f2bf((v0.z - mu) * rs * g0.z + b0.z);
    ov[3] = (short)f2bf((v0.w - mu) * rs * g0.w + b0.w);
    ov[4] = (short)f2bf((v1.x - mu) * rs * g1.x + b1.x);
    ov[5] = (short)f2bf((v1.y - mu) * rs * g1.y + b1.y);
    ov[6] = (short)f2bf((v1.z - mu) * rs * g1.z + b1.z);
    ov[7] = (short)f2bf((v1.w - mu) * rs * g1.w + b1.w);
    *(bh8*)(xn + (size_t)row * 512 + lane * 8) = ov;
    return;
  }

  // -------- weight-GEMM branch --------
  const int bx = blockIdx.x;
  const int wave = tid >> 6, lane = tid & 63;
  const int quad = lane >> 4, l16 = lane & 15;
  const int wm = (wave >> 1) * 64, wn = (wave & 1) * 64;
  int role, mb, nb;
  if (bx < 10)      { role = 0; mb = bx >> 1; nb = bx & 1; }
  else if (bx < 14) { role = 1; mb = 0; nb = bx - 10; }
  else { role = 2; int t = bx - 14; mb = t >> 2; nb = t & 3; }
  const bf16_t* Ap = (role == 1) ? Wso_b : Win_b;
  const bf16_t* Bp = (role == 0) ? Wcat_t : (role == 1) ? Wout_t : Wdout_t;

  f4 acc[4][4];
  #pragma unroll
  for (int i = 0; i < 4; ++i)
    #pragma unroll
    for (int j = 0; j < 4; ++j) acc[i][j] = (f4){0.f, 0.f, 0.f, 0.f};

  for (int kt = 0; kt < 8; ++kt) {
    const int k0 = kt << 6;
    __syncthreads();
    #pragma unroll
    for (int i = 0; i < 4; ++i) {
      const int base = (wave * 4 + i) * 64;
      const int cid = base + lane;
      const int row = cid >> 3;
      const int g = (cid & 7) ^ (row & 7);
      async_cp16((char*)As + base * 16,
                 Ap + (size_t)(mb * 128 + row) * 512 + k0 + g * 8);
    }
    #pragma unroll
    for (int i = 0; i < 4; ++i) {
      const int base = (wave * 4 + i) * 64;
      const int cid = base + lane;
      const int row = cid >> 3;
      const int g = (cid & 7) ^ (row & 7);
      async_cp16((char*)Bs + base * 16,
                 Bp + (size_t)(nb * 128 + row) * 512 + k0 + g * 8);
    }
    __syncthreads();
    #pragma unroll
    for (int ks = 0; ks < 2; ++ks) {
      const int gb = ks * 4 + quad;
      bh8 af[4], bfv[4];
      #pragma unroll
      for (int im = 0; im < 4; ++im) {
        const int row = wm + im * 16 + l16;
        af[im] = *(const bh8*)((const char*)As + row * 128 + ((gb ^ (row & 7)) * 16));
      }
      #pragma unroll
      for (int in_ = 0; in_ < 4; ++in_) {
        const int row = wn + in_ * 16 + l16;
        bfv[in_] = *(const bh8*)((const char*)Bs + row * 128 + ((gb ^ (row & 7)) * 16));
      }
      #pragma unroll
      for (int im = 0; im < 4; ++im)
        #pragma unroll
        for (int in_ = 0; in_ < 4; ++in_)
          acc[im][in_] = __builtin_amdgcn_mfma_f32_16x16x32_bf16(af[im], bfv[in_],
                                                                 acc[im][in_], 0, 0, 0);
    }
  }

  #pragma unroll
  for (int im = 0; im < 4; ++im) {
    #pragma unroll
    for (int in_ = 0; in_ < 4; ++in_) {
      const int row0 = mb * 128 + wm + im * 16 + quad * 4;
      const int col = nb * 128 + wn + in_ * 16 + l16;
      if (role == 0) {
        if (col < 192) {
          if (row0 < 512) {
            *(uint2*)(Wproj + (size_t)col * 512 + row0) = pack4bf(acc[im][in_]);
          } else if (row0 == 512) {
            float v = acc[im][in_][0];
            if (col < 128) { int w = col & 31;
              if (w >= 16) v += b_B[(col >> 5) * 16 + (w - 16)];
            } else v += b_C[col - 128];
            biasp[col] = v;
          }
        }
      } else if (role == 1) {
        if (row0 < 64)
          *(uint2*)(Wcat2 + (size_t)col * 576 + row0) = pack4bf(acc[im][in_]);
      } else {
        if (row0 < 512) {
          *(uint2*)(Wcat2 + (size_t)col * 576 + 64 + row0) = pack4bf(acc[im][in_]);
        } else if (row0 == 512) {
          biasW2[col] = acc[im][in_][0];
        }
      }
    }
  }
}

// ---------------- gemm_proj: 128x128 tile, BK=64, XCD-grouped decode --------
// projP = xn @ Wproj^T (+biasp). grid 512 (1D): xcd=bid&7, t=bid>>3,
// nb=t&1, mb=xcd*32+(t>>1) -- the 2 nb-siblings sharing an A-tile run
// adjacently on one XCD's L2.
//   nb==0: interleaved xs/B cols -> Bx = xs*B, plane 0, + fused chunk carries.
//   nb==1: cols 128..191 (C) -> plane 1 (wn==0 waves only).
__global__ __launch_bounds__(256, 4) void gemm_proj(
    const bf16_t* __restrict__ A0, const bf16_t* __restrict__ Wt,
    float* __restrict__ outf, const float* __restrict__ bias1,
    const float* __restrict__ Abar, float* __restrict__ carryT) {
  __shared__ __align__(16) char smem[32768];
  bf16_t* As = (bf16_t*)smem;
  bf16_t* Bs = (bf16_t*)(smem + 16384);
  const int tid = threadIdx.x;
  const int wave = tid >> 6, lane = tid & 63;
  const int quad = lane >> 4, l16 = lane & 15;
  const int wm = (wave >> 1) * 64, wn = (wave & 1) * 64;
  const int bid = blockIdx.x;
  const int xcd = bid & 7, t0 = bid >> 3;
  const int nb = t0 & 1, mb = xcd * 32 + (t0 >> 1);
  const int K = 512;

  f4 acc[4][4];
  #pragma unroll
  for (int i = 0; i < 4; ++i)
    #pragma unroll
    for (int j = 0; j < 4; ++j) acc[i][j] = (f4){0.f, 0.f, 0.f, 0.f};

  for (int kt = 0; kt < 8; ++kt) {
    const int k0 = kt << 6;
    __syncthreads();
    #pragma unroll
    for (int i = 0; i < 4; ++i) {
      const int base = (wave * 4 + i) * 64;
      const int cid = base + lane;
      const int row = cid >> 3;
      const int g = (cid & 7) ^ (row & 7);
      async_cp16((char*)As + base * 16,
                 A0 + (size_t)(mb * 128 + row) * K + k0 + g * 8);
    }
    #pragma unroll
    for (int i = 0; i < 4; ++i) {
      const int base = (wave * 4 + i) * 64;
      const int cid = base + lane;
      const int row = cid >> 3;
      const int g = (cid & 7) ^ (row & 7);
      async_cp16((char*)Bs + base * 16,
                 Wt + (size_t)(nb * 128 + row) * K + k0 + g * 8);
    }
    __syncthreads();

    #pragma unroll
    for (int ks = 0; ks < 2; ++ks) {
      const int gb = ks * 4 + quad;
      bh8 af[4], bfv[4];
      #pragma unroll
      for (int im = 0; im < 4; ++im) {
        const int row = wm + im * 16 + l16;
        af[im] = *(const bh8*)((const char*)As + row * 128 + ((gb ^ (row & 7)) * 16));
      }
      #pragma unroll
      for (int in_ = 0; in_ < 4; ++in_) {
        const int row = wn + in_ * 16 + l16;
        bfv[in_] = *(const bh8*)((const char*)Bs + row * 128 + ((gb ^ (row & 7)) * 16));
      }
      #pragma unroll
      for (int im = 0; im < 4; ++im)
        #pragma unroll
        for (int in_ = 0; in_ < 4; ++in_)
          acc[im][in_] = __builtin_amdgcn_mfma_f32_16x16x32_bf16(af[im], bfv[in_],
                                                                 acc[im][in_], 0, 0, 0);
    }
  }

  __syncthreads();
  float* lt = (float*)smem;

  if (nb == 0) {
    // interleaved xs/B: fuse Bx = xs*B into wave-private LDS tile
    float* wb = lt + wave * 2048;            // 64 rows x 32 chains fp32 = 8KB
    #pragma unroll
    for (int im = 0; im < 4; ++im)
      #pragma unroll
      for (int pp = 0; pp < 2; ++pp)
        #pragma unroll
        for (int r = 0; r < 4; ++r) {
          const int c0 = wn + (2 * pp) * 16 + l16;
          const float vx = acc[im][2 * pp][r]     + bias1[c0];
          const float vb = acc[im][2 * pp + 1][r] + bias1[c0 + 16];
          wb[(im * 16 + quad * 4 + r) * 32 + pp * 16 + l16] = vx * vb;
        }
    const int rsub = lane >> 3, cg8 = lane & 7;
    #pragma unroll
    for (int rr = 0; rr < 8; ++rr) {
      const int rl = rr * 8 + rsub;
      f4 v = *(f4*)(wb + rl * 32 + cg8 * 4);
      const size_t row = (size_t)(mb * 128 + wm + rl);
      *(f4*)(outf + row * 64 + (wn >> 1) + cg8 * 4) = v;
    }
    // fused chunk-local scan carries (16-step chunks from the LDS Bx tile)
    {
      const int bb = mb >> 5;                       // batch (32 blocks/batch)
      const int cbase = (mb & 31) * 8 + (wm >> 4);  // first chunk of this wave
      const int ch = lane & 31;                     // chain_local
      const int n = (wn >> 1) + ch;                 // global chain 0..63
      const float A = Abar[n];
      #pragma unroll
      for (int t = 0; t < 2; ++t) {
        const int cl = (lane >> 5) + 2 * t;         // chunk_local 0..3
        float hv = 0.f;
        #pragma unroll
        for (int i = 0; i < SCAN_L; ++i)
          hv = fmaf(A, hv, wb[(cl * SCAN_L + i) * 32 + ch]);
        carryT[(size_t)(cbase + cl) * 512 + bb * 64 + n] = hv;
      }
    }
  } else if (wn == 0) {
    // C plane: global cols 128..191 -> chains 0..63 (waves 0 and 2 only)
    float* wb = lt + (wave >> 1) * 4096;     // 64 rows x 64 chains fp32 = 16KB
    #pragma unroll
    for (int im = 0; im < 4; ++im)
      #pragma unroll
      for (int in_ = 0; in_ < 4; ++in_)
        #pragma unroll
        for (int r = 0; r < 4; ++r) {
          const int c = in_ * 16 + l16;
          wb[(im * 16 + quad * 4 + r) * 64 + c] = acc[im][in_][r] + bias1[128 + c];
        }
    #pragma unroll
    for (int rr = 0; rr < 16; ++rr) {
      const int rl = rr * 4 + quad;
      f4 v = *(f4*)(wb + rl * 64 + l16 * 4);
      const size_t row = (size_t)(mb * 128 + wm + rl);
      *(f4*)(outf + ((size_t)M_ROWS + row) * 64 + l16 * 4) = v;
    }
  }
}

// ---------------- gemm_out: 64x128 tile, BK=64, XCD-grouped decode ----------
// out = [CH|xn] @ Wcat2^T + b_out + biasW2 + x   (K=576), grid 2048 (1D):
// xcd=bid&7, t=bid>>3, nb=t&3, mb=xcd*64+(t>>2) -- 4 nb-siblings sharing an
// A-tile (CH+xn rows) run adjacently on one XCD's L2.
// K-loop/epilogue = round-10 (single buffer, 2-barrier, scalar epilogue);
// resid via nontemporal LOAD (avoids 28MB write-allocate FETCH), store regular.
__global__ __launch_bounds__(256, 6) void gemm_out(
    const bf16_t* __restrict__ CH, const bf16_t* __restrict__ xn,
    const bf16_t* __restrict__ Wt, float* __restrict__ outf,
    const float* __restrict__ bias0, const float* __restrict__ bias1,
    const float* __restrict__ resid) {
  __shared__ __align__(16) bf16_t As[64 * 64];    // 8KB
  __shared__ __align__(16) bf16_t Bs[128 * 64];   // 16KB
  const int tid = threadIdx.x;
  const int wave = tid >> 6, lane = tid & 63;
  const int quad = lane >> 4, l16 = lane & 15;
  const int wm = (wave >> 1) * 32, wn = (wave & 1) * 64;
  const int bid = blockIdx.x;
  const int xcd = bid & 7, t0 = bid >> 3;
  const int nb = t0 & 3, mb = xcd * 64 + (t0 >> 2);
  const int K = 576;

  f4 acc[2][4];
  #pragma unroll
  for (int i = 0; i < 2; ++i)
    #pragma unroll
    for (int j = 0; j < 4; ++j) acc[i][j] = (f4){0.f, 0.f, 0.f, 0.f};

  for (int kt = 0; kt < 9; ++kt) {
    const int k0 = kt << 6;
    const bf16_t* Ap; int lda, kk;
    if (kt == 0) { Ap = CH; lda = 64;  kk = 0; }        // CH tile (K 0..63)
    else         { Ap = xn; lda = 512; kk = k0 - 64; }  // xn tile

    __syncthreads();
    #pragma unroll
    for (int i = 0; i < 2; ++i) {             // A: 64 rows, 8KB
      const int base = (wave * 2 + i) * 64;
      const int cid = base + lane;
      const int row = cid >> 3;
      const int g = (cid & 7) ^ (row & 7);
      async_cp16((char*)As + base * 16,
                 Ap + (size_t)(mb * 64 + row) * lda + kk + g * 8);
    }
    #pragma unroll
    for (int i = 0; i < 4; ++i) {             // B: 128 rows, 16KB
      const int base = (wave * 4 + i) * 64;
      const int cid = base + lane;
      const int row = cid >> 3;
      const int g = (cid & 7) ^ (row & 7);
      async_cp16((char*)Bs + base * 16,
                 Wt + (size_t)(nb * 128 + row) * K + k0 + g * 8);
    }
    __syncthreads();

    #pragma unroll
    for (int ks = 0; ks < 2; ++ks) {
      const int gb = ks * 4 + quad;
      bh8 af[2], bfv[4];
      #pragma unroll
      for (int im = 0; im < 2; ++im) {
        const int row = wm + im * 16 + l16;
        af[im] = *(const bh8*)((const char*)As + row * 128 + ((gb ^ (row & 7)) * 16));
      }
      #pragma unroll
      for (int in_ = 0; in_ < 4; ++in_) {
        const int row = wn + in_ * 16 + l16;
        bfv[in_] = *(const bh8*)((const char*)Bs + row * 128 + ((gb ^ (row & 7)) * 16));
      }
      #pragma unroll
      for (int im = 0; im < 2; ++im)
        #pragma unroll
        for (int in_ = 0; in_ < 4; ++in_)
          acc[im][in_] = __builtin_amdgcn_mfma_f32_16x16x32_bf16(af[im], bfv[in_],
                                                                 acc[im][in_], 0, 0, 0);
    }
  }

  // ---- direct epilogue: acc layout col=l16, row=quad*4+reg. Scalar I/O,
  // nontemporal resid LOAD (no L2 write-allocate pollution), REGULAR store
  // (nt stores shown to inflate WRITE_SIZE 15-20MB: R8/R13 vs R10/R12).
  #pragma unroll
  for (int im = 0; im < 2; ++im) {
    #pragma unroll
    for (int in_ = 0; in_ < 4; ++in_) {
      const int col = nb * 128 + wn + in_ * 16 + l16;
      const float bsum = bias0[col] + bias1[col];
      #pragma unroll
      for (int r = 0; r < 4; ++r) {
        const int row = mb * 64 + wm + im * 16 + quad * 4 + r;
        const size_t idx = (size_t)row * 512 + col;
        const float rv = __builtin_nontemporal_load(resid + idx);
        outf[idx] = acc[im][in_][r] + bsum + rv;
      }
    }
  }
}

// ---------------- scan_apply: carry-in recombine + chunk replay --------------
// carryT is TRANSPOSED: carryT[c * 512 + b*64 + n] (coalesced across lanes).
// projP planes: 0 = Bx, 1 = C.
__global__ __launch_bounds__(64) void scan_apply(
    const float* __restrict__ projP, const float* __restrict__ Abar,
    const float* __restrict__ Apow, const float* __restrict__ carryT,
    bf16_t* __restrict__ CH) {
  const int b = blockIdx.x >> 8, c = blockIdx.x & (SCAN_C - 1), n = threadIdx.x;
  const float A = Abar[n];
  const float Ap = Apow[n];
  const float Ap4 = (Ap * Ap) * (Ap * Ap);
  const float* cr = carryT + b * 64 + n;
  float h0 = 0.f, h1 = 0.f, h2 = 0.f, h3 = 0.f;
  int j = 0;
  for (; j + 4 <= c; j += 4) {
    h0 = fmaf(Ap4, h0, cr[(size_t)j * 512]);
    h1 = fmaf(Ap4, h1, cr[(size_t)(j + 1) * 512]);
    h2 = fmaf(Ap4, h2, cr[(size_t)(j + 2) * 512]);
    h3 = fmaf(Ap4, h3, cr[(size_t)(j + 3) * 512]);
  }
  float h = fmaf(Ap, fmaf(Ap, fmaf(Ap, h0, h1), h2), h3);
  for (; j < c; ++j) h = fmaf(Ap, h, cr[(size_t)j * 512]);
  const size_t row0 = (size_t)b * 4096 + c * SCAN_L;
  const float* pBx = projP + row0 * 64;
  const float* pC  = projP + ((size_t)M_ROWS + row0) * 64;
  bf16_t* o = CH + row0 * 64;
  for (int i = 0; i < SCAN_L; ++i) {
    h = fmaf(A, h, pBx[i * 64 + n]);
    o[i * 64 + n] = f2bf(pC[i * 64 + n] * h);
  }
}

// ---------------- launch ----------------
extern "C" void kernel_launch(void* const* d_in, const int* in_sizes, int n_in,
                              void* d_out, int out_size, void* d_ws, size_t ws_size,
                              hipStream_t stream) {
  const float* x      = (const float*)d_in[0];
  const float* ln_g   = (const float*)d_in[1];
  const float* ln_b   = (const float*)d_in[2];
  const float* W_in   = (const float*)d_in[3];
  const float* b_in   = (const float*)d_in[4];
  const float* W_xs   = (const float*)d_in[5];
  const float* W_B    = (const float*)d_in[6];
  const float* b_B    = (const float*)d_in[7];
  const float* W_C    = (const float*)d_in[8];
  const float* b_C    = (const float*)d_in[9];
  const float* A_log  = (const float*)d_in[10];
  const float* D_skip = (const float*)d_in[11];
  const float* W_so   = (const float*)d_in[12];
  const float* W_out  = (const float*)d_in[13];
  const float* b_out  = (const float*)d_in[14];
  float* out = (float*)d_out;

  char* w = (char*)d_ws;
  auto carve = [&](size_t bytes) {
    char* p = w; w += (bytes + 255) & ~(size_t)255; return p;
  };
  bf16_t* xn     = (bf16_t*)carve((size_t)M_ROWS * 512 * 2);
  float*  projP  = (float*)carve((size_t)2 * M_ROWS * 64 * 4);
  bf16_t* CH     = (bf16_t*)carve((size_t)M_ROWS * 64 * 2);
  float*  carryT = (float*)carve((size_t)SCAN_C * 512 * 4);
  bf16_t* Wproj  = (bf16_t*)carve((size_t)256 * 512 * 2);
  bf16_t* Wcat2  = (bf16_t*)carve((size_t)512 * 576 * 2);
  bf16_t* Win_b  = (bf16_t*)carve((size_t)640 * 512 * 2);
  bf16_t* Wso_b  = (bf16_t*)carve((size_t)128 * 512 * 2);
  bf16_t* Wout_t = (bf16_t*)carve((size_t)512 * 512 * 2);
  bf16_t* Wdout_t= (bf16_t*)carve((size_t)512 * 512 * 2);
  bf16_t* Wcat_t = (bf16_t*)carve((size_t)256 * 512 * 2);
  float*  biasp  = (float*)carve(192 * 4);
  float*  biasW2 = (float*)carve(512 * 4);
  float*  Abar   = (float*)carve(256);
  float*  Apow   = (float*)carve(256);

  prep_all<<<4227, 256, 0, stream>>>(W_in, W_out, W_so, W_xs, W_B, W_C, b_in,
                                     D_skip, A_log, Wout_t, Wdout_t, Win_b,
                                     Wso_b, Wcat_t, Wproj, Abar, Apow);
  prep2_fused<<<34 + 8192, 256, 0, stream>>>(Win_b, Wcat_t, Wso_b, Wout_t,
                                             Wdout_t, b_B, b_C, Wproj, Wcat2,
                                             biasp, biasW2, x, ln_g, ln_b, xn);
  gemm_proj<<<512, 256, 0, stream>>>(xn, Wproj, projP, biasp,
                                     Abar, carryT);
  scan_apply<<<8 * SCAN_C, 64, 0, stream>>>(projP, Abar, Apow, carryT, CH);
  gemm_out<<<2048, 256, 0, stream>>>(CH, xn, Wcat2, out,
                                     b_out, biasW2, x);
}